// Round 1
// baseline (483.826 us; speedup 1.0000x reference)
//
#include <hip/hip_runtime.h>

// RouterModel: top-1-of-2 softmax router with dense dispatch.
//   score = softmax(x @ W)          [N,2]
//   path  = argmax(score)           (tie -> 0, numpy first-occurrence)
//   x0 = x * (path==0 ? p0 : 0); x1 = x * (path==1 ? p1 : 0); xc = x0 + x1
// Memory-bound: read 134 MB, write 403 MB -> ~85 us floor at 6.3 TB/s.

constexpr int kN = 32768;
constexpr int kD = 1024;
constexpr long long kND = (long long)kN * kD;

// One wave (64 lanes) per token. Lane l holds float4 indices {l, l+64, l+128, l+192}
// of the 256-float4 row: coalesced 16B/lane loads, row stays in registers for
// the 3 output stores.
__global__ __launch_bounds__(256) void router_kernel(
    const float* __restrict__ x, const float* __restrict__ W,
    float* __restrict__ out)
{
    const int wave_in_blk = threadIdx.x >> 6;
    const int lane        = threadIdx.x & 63;
    const int t           = blockIdx.x * 4 + wave_in_blk;   // token id
    if (t >= kN) return;

    const float4* __restrict__ row4 = (const float4*)(x + (long long)t * kD);
    const float4* __restrict__ W4   = (const float4*)W;     // interleaved [D,2]

    float4 v[4];
    float s0 = 0.f, s1 = 0.f;
#pragma unroll
    for (int j = 0; j < 4; ++j) {
        const int idx = lane + j * 64;          // float4 index within row, 0..255
        v[j] = row4[idx];
        // elements d = 4*idx .. 4*idx+3 ; W[2d .. 2d+7] = two float4s
        const float4 wa = W4[2 * idx];          // {W0[d],W1[d],W0[d+1],W1[d+1]}
        const float4 wb = W4[2 * idx + 1];      // {W0[d+2],W1[d+2],W0[d+3],W1[d+3]}
        s0 += v[j].x * wa.x + v[j].y * wa.z + v[j].z * wb.x + v[j].w * wb.z;
        s1 += v[j].x * wa.y + v[j].y * wa.w + v[j].z * wb.y + v[j].w * wb.w;
    }

    // 64-lane butterfly reduction (wave = 64 on CDNA)
#pragma unroll
    for (int off = 32; off >= 1; off >>= 1) {
        s0 += __shfl_xor(s0, off, 64);
        s1 += __shfl_xor(s1, off, 64);
    }

    // 2-way softmax (exact fp32) + first-occurrence argmax
    const float m   = fmaxf(s0, s1);
    const float e0  = expf(s0 - m);
    const float e1  = expf(s1 - m);
    const float inv = 1.f / (e0 + e1);
    const float p0  = e0 * inv;
    const float p1  = e1 * inv;
    const int path  = (s1 > s0) ? 1 : 0;        // tie -> 0, matches jnp.argmax
    const float g0  = (path == 0) ? p0 : 0.f;
    const float g1  = (path == 1) ? p1 : 0.f;
    const float gc  = g0 + g1;                  // == max(p0,p1)

    float4* __restrict__ o0 = (float4*)(out +            (long long)t * kD);
    float4* __restrict__ o1 = (float4*)(out + kND      + (long long)t * kD);
    float4* __restrict__ oc = (float4*)(out + 2 * kND  + (long long)t * kD);
#pragma unroll
    for (int j = 0; j < 4; ++j) {
        const int idx = lane + j * 64;
        o0[idx] = make_float4(v[j].x * g0, v[j].y * g0, v[j].z * g0, v[j].w * g0);
        o1[idx] = make_float4(v[j].x * g1, v[j].y * g1, v[j].z * g1, v[j].w * g1);
        oc[idx] = make_float4(v[j].x * gc, v[j].y * gc, v[j].z * gc, v[j].w * gc);
    }
}

extern "C" void kernel_launch(void* const* d_in, const int* in_sizes, int n_in,
                              void* d_out, int out_size, void* d_ws, size_t ws_size,
                              hipStream_t stream)
{
    const float* x = (const float*)d_in[0];   // [N, D] fp32
    const float* W = (const float*)d_in[1];   // [D, 2] fp32
    float* out     = (float*)d_out;           // x0 | x1 | xc, each [N, D]

    // 4 waves per 256-thread block, one wave per token.
    const int blocks = kN / 4;                // 8192
    router_kernel<<<blocks, 256, 0, stream>>>(x, W, out);
}